// Round 1
// baseline (165.717 us; speedup 1.0000x reference)
//
#include <hip/hip_runtime.h>
#include <stdint.h>
#include <stddef.h>

typedef __bf16 bf16x8 __attribute__((ext_vector_type(8)));
typedef __bf16 bf16x4 __attribute__((ext_vector_type(4)));
typedef float  f32x4  __attribute__((ext_vector_type(4)));

#define MFMA16(A, B, C) __builtin_amdgcn_mfma_f32_16x16x32_bf16((A), (B), (C), 0, 0, 0)

// ---------------------------------------------------------------------------
// Kernel 1: fused QKV projection.
//   x [32768][768] fp32  x  W[768][64] (q,k,v) -> Q,K bf16 [32768][64],
//   V written TRANSPOSED per batch: Vt [8][64][4096] bf16 (so attention's
//   PV B-fragment reads are contiguous).
// GEMM M=32768, Nfused=192, K=768.  Block: 256 thr (4 waves), tile 64x192,
// BK=32. LDS x-tile [64][40] (pad) + W^T tile [192][40] (pad).
// ---------------------------------------------------------------------------
__global__ __launch_bounds__(256) void qkv_proj_kernel(
    const float* __restrict__ x,
    const float* __restrict__ Wq, const float* __restrict__ bq,
    const float* __restrict__ Wk, const float* __restrict__ bk,
    const float* __restrict__ Wv, const float* __restrict__ bv,
    __bf16* __restrict__ Qg, __bf16* __restrict__ Kg, __bf16* __restrict__ Vtg)
{
    __shared__ __bf16 xs[64][40];    // [row][k]  pad 32->40 (2-way banks)
    __shared__ __bf16 wt[192][40];   // [col][k]  transposed W tile

    const int tid  = threadIdx.x;
    const int wid  = tid >> 6;
    const int lane = tid & 63;
    const int l15  = lane & 15;
    const int l4   = lane >> 4;
    const int m0   = blockIdx.x * 64;

    f32x4 acc[4][3];
    #pragma unroll
    for (int i = 0; i < 4; ++i)
        #pragma unroll
        for (int j = 0; j < 3; ++j)
            acc[i][j] = (f32x4){0.f, 0.f, 0.f, 0.f};

    for (int k0 = 0; k0 < 768; k0 += 32) {
        // stage x tile 64x32 (fp32 -> bf16)
        #pragma unroll
        for (int i = 0; i < 2; ++i) {
            int idx = tid + 256 * i;       // 0..511
            int row = idx >> 3;            // 64 rows
            int c4  = idx & 7;             // 8 float4 per row
            const float4 v = *reinterpret_cast<const float4*>(
                x + (size_t)(m0 + row) * 768 + k0 + c4 * 4);
            bf16x4 t;
            t[0] = (__bf16)v.x; t[1] = (__bf16)v.y;
            t[2] = (__bf16)v.z; t[3] = (__bf16)v.w;
            *reinterpret_cast<bf16x4*>(&xs[row][c4 * 4]) = t;
        }
        // stage W^T tile: wt[col 0..191][k 0..31]
        #pragma unroll
        for (int i = 0; i < 6; ++i) {
            int idx = tid + 256 * i;       // 0..1535
            int kg  = idx / 192;           // 0..7  (group of 4 k)
            int c   = idx - kg * 192;      // 0..191
            const float* Wm = (c < 64) ? Wq : ((c < 128) ? Wk : Wv);
            int cc = c & 63;
            bf16x4 t;
            #pragma unroll
            for (int j = 0; j < 4; ++j)
                t[j] = (__bf16)Wm[(size_t)(k0 + kg * 4 + j) * 64 + cc];
            *reinterpret_cast<bf16x4*>(&wt[c][kg * 4]) = t;
        }
        __syncthreads();

        bf16x8 afrag[4];
        #pragma unroll
        for (int rf = 0; rf < 4; ++rf)
            afrag[rf] = *reinterpret_cast<const bf16x8*>(&xs[rf * 16 + l15][l4 * 8]);
        #pragma unroll
        for (int cf = 0; cf < 3; ++cf) {
            bf16x8 bfrag = *reinterpret_cast<const bf16x8*>(
                &wt[wid * 48 + cf * 16 + l15][l4 * 8]);
            #pragma unroll
            for (int rf = 0; rf < 4; ++rf)
                acc[rf][cf] = MFMA16(afrag[rf], bfrag, acc[rf][cf]);
        }
        __syncthreads();
    }

    // epilogue: bias add, write Q/K row-major, V transposed
    #pragma unroll
    for (int cf = 0; cf < 3; ++cf) {
        int col = wid * 48 + cf * 16 + l15;   // 0..191
        int mi  = col >> 6;                   // 0=Q 1=K 2=V
        int h   = col & 63;
        float bias = (mi == 0) ? bq[h] : ((mi == 1) ? bk[h] : bv[h]);
        #pragma unroll
        for (int rf = 0; rf < 4; ++rf) {
            int r0 = rf * 16 + l4 * 4;        // local row base (4 consecutive)
            if (mi == 2) {
                int m  = m0 + r0;
                int bb = m >> 12;             // batch
                int n0 = m & 4095;            // token within batch
                bf16x4 t;
                #pragma unroll
                for (int r = 0; r < 4; ++r)
                    t[r] = (__bf16)(acc[rf][cf][r] + bias);
                *reinterpret_cast<bf16x4*>(
                    Vtg + ((size_t)bb * 64 + h) * 4096 + n0) = t;
            } else {
                __bf16* G = (mi == 0) ? Qg : Kg;
                #pragma unroll
                for (int r = 0; r < 4; ++r)
                    G[(size_t)(m0 + r0 + r) * 64 + h] =
                        (__bf16)(acc[rf][cf][r] + bias);
            }
        }
    }
}

// ---------------------------------------------------------------------------
// Kernel 2: flash attention (non-causal), one block = one batch x 64 q-rows.
// 4 waves, each wave owns 16 q-rows. KBLK=64 keys per iteration.
// Q fragments in registers; K tile + Vt tile staged in LDS; P round-trips
// through a per-wave LDS buffer to move C-layout -> A-fragment layout.
// ---------------------------------------------------------------------------
__global__ __launch_bounds__(256) void attn_kernel(
    const __bf16* __restrict__ Qg, const __bf16* __restrict__ Kg,
    const __bf16* __restrict__ Vtg, float* __restrict__ out)
{
    __shared__ __bf16 ks[64][72];      // K tile  [key][d]   (pad 64->72)
    __shared__ __bf16 vs[64][72];      // Vt tile [h][key]
    __shared__ __bf16 ps[4][16][72];   // per-wave P tile [q][key]

    const int tid  = threadIdx.x;
    const int wid  = tid >> 6;
    const int lane = tid & 63;
    const int l15  = lane & 15;
    const int l4   = lane >> 4;
    const int b    = blockIdx.x >> 6;          // batch
    const int q0   = (blockIdx.x & 63) * 64;   // q-tile base
    const int qw   = q0 + wid * 16;            // this wave's q rows

    // Q fragments (A-operand): 16 rows x 64 d
    bf16x8 aq[2];
    #pragma unroll
    for (int dc = 0; dc < 2; ++dc)
        aq[dc] = *reinterpret_cast<const bf16x8*>(
            Qg + (size_t)(b * 4096 + qw + l15) * 64 + dc * 32 + l4 * 8);

    float m_r[4], l_r[4];
    f32x4 o[4];
    #pragma unroll
    for (int r = 0; r < 4; ++r) { m_r[r] = -1e30f; l_r[r] = 0.f; }
    #pragma unroll
    for (int cf = 0; cf < 4; ++cf) o[cf] = (f32x4){0.f, 0.f, 0.f, 0.f};

    for (int kt = 0; kt < 64; ++kt) {
        // stage K[kt*64 .. +63][0..63] and Vt[0..63][kt*64 .. +63]
        #pragma unroll
        for (int i = 0; i < 2; ++i) {
            int idx = tid + 256 * i;   // 0..511
            int r   = idx >> 3;        // 64 rows
            int c8  = idx & 7;         // 8 groups of 8 bf16
            bf16x8 kv = *reinterpret_cast<const bf16x8*>(
                Kg + (size_t)(b * 4096 + kt * 64 + r) * 64 + c8 * 8);
            *reinterpret_cast<bf16x8*>(&ks[r][c8 * 8]) = kv;
            bf16x8 vv = *reinterpret_cast<const bf16x8*>(
                Vtg + (size_t)(b * 64 + r) * 4096 + kt * 64 + c8 * 8);
            *reinterpret_cast<bf16x8*>(&vs[r][c8 * 8]) = vv;
        }
        __syncthreads();

        // S = Q K^T : 4 col-frags (16 keys each), K-dim 64 in 2 chunks
        f32x4 s[4];
        #pragma unroll
        for (int cf = 0; cf < 4; ++cf) s[cf] = (f32x4){0.f, 0.f, 0.f, 0.f};
        #pragma unroll
        for (int dc = 0; dc < 2; ++dc) {
            #pragma unroll
            for (int cf = 0; cf < 4; ++cf) {
                bf16x8 bk = *reinterpret_cast<const bf16x8*>(
                    &ks[cf * 16 + l15][dc * 32 + l4 * 8]);
                s[cf] = MFMA16(aq[dc], bk, s[cf]);
            }
        }
        #pragma unroll
        for (int cf = 0; cf < 4; ++cf)
            #pragma unroll
            for (int r = 0; r < 4; ++r)
                s[cf][r] *= 0.125f;

        // online softmax: row = 4*l4 + r; 64 keys spread over 16 lanes x 4 cf
        float pm[4];
        #pragma unroll
        for (int r = 0; r < 4; ++r) {
            float v = fmaxf(fmaxf(s[0][r], s[1][r]), fmaxf(s[2][r], s[3][r]));
            v = fmaxf(v, __shfl_xor(v, 1));
            v = fmaxf(v, __shfl_xor(v, 2));
            v = fmaxf(v, __shfl_xor(v, 4));
            v = fmaxf(v, __shfl_xor(v, 8));
            pm[r] = v;
        }
        #pragma unroll
        for (int r = 0; r < 4; ++r) {
            float nm = fmaxf(m_r[r], pm[r]);
            float fr = __expf(m_r[r] - nm);
            m_r[r] = nm;
            l_r[r] *= fr;
            #pragma unroll
            for (int cf = 0; cf < 4; ++cf) o[cf][r] *= fr;
        }
        float psum[4] = {0.f, 0.f, 0.f, 0.f};
        #pragma unroll
        for (int cf = 0; cf < 4; ++cf)
            #pragma unroll
            for (int r = 0; r < 4; ++r) {
                float p = __expf(s[cf][r] - m_r[r]);
                s[cf][r] = p;
                psum[r] += p;
            }
        #pragma unroll
        for (int r = 0; r < 4; ++r) {
            float v = psum[r];
            v += __shfl_xor(v, 1);
            v += __shfl_xor(v, 2);
            v += __shfl_xor(v, 4);
            v += __shfl_xor(v, 8);
            l_r[r] += v;
        }

        // P (C-layout) -> per-wave LDS -> A-fragment layout
        #pragma unroll
        for (int cf = 0; cf < 4; ++cf)
            #pragma unroll
            for (int r = 0; r < 4; ++r)
                ps[wid][l4 * 4 + r][cf * 16 + l15] = (__bf16)s[cf][r];

        // O += P V  (B = Vt rows are h, contiguous in key)
        #pragma unroll
        for (int kc = 0; kc < 2; ++kc) {
            bf16x8 pa = *reinterpret_cast<const bf16x8*>(
                &ps[wid][l15][kc * 32 + l4 * 8]);
            #pragma unroll
            for (int cf = 0; cf < 4; ++cf) {
                bf16x8 bv = *reinterpret_cast<const bf16x8*>(
                    &vs[cf * 16 + l15][kc * 32 + l4 * 8]);
                o[cf] = MFMA16(pa, bv, o[cf]);
            }
        }
        __syncthreads();
    }

    // epilogue: normalize and store fp32
    #pragma unroll
    for (int cf = 0; cf < 4; ++cf) {
        #pragma unroll
        for (int r = 0; r < 4; ++r) {
            int q = qw + l4 * 4 + r;
            out[(size_t)(b * 4096 + q) * 64 + cf * 16 + l15] = o[cf][r] / l_r[r];
        }
    }
}

extern "C" void kernel_launch(void* const* d_in, const int* in_sizes, int n_in,
                              void* d_out, int out_size, void* d_ws, size_t ws_size,
                              hipStream_t stream)
{
    (void)in_sizes; (void)n_in; (void)out_size; (void)ws_size;
    const float* x  = (const float*)d_in[0];
    const float* Wq = (const float*)d_in[1];
    const float* bq = (const float*)d_in[2];
    const float* Wk = (const float*)d_in[3];
    const float* bk = (const float*)d_in[4];
    const float* Wv = (const float*)d_in[5];
    const float* bv = (const float*)d_in[6];
    float* out = (float*)d_out;

    __bf16* Qg  = (__bf16*)d_ws;                    // [32768][64] bf16
    __bf16* Kg  = Qg + (size_t)32768 * 64;          // [32768][64] bf16
    __bf16* Vtg = Kg + (size_t)32768 * 64;          // [8][64][4096] bf16

    qkv_proj_kernel<<<512, 256, 0, stream>>>(x, Wq, bq, Wk, bk, Wv, bv, Qg, Kg, Vtg);
    attn_kernel<<<512, 256, 0, stream>>>(Qg, Kg, Vtg, out);
}

// Round 2
// 131.018 us; speedup vs baseline: 1.2648x; 1.2648x over previous
//
#include <hip/hip_runtime.h>
#include <stdint.h>
#include <stddef.h>

typedef __bf16 bf16x8 __attribute__((ext_vector_type(8)));
typedef __bf16 bf16x4 __attribute__((ext_vector_type(4)));
typedef float  f32x4  __attribute__((ext_vector_type(4)));

#define MFMA16(A, B, C) __builtin_amdgcn_mfma_f32_16x16x32_bf16((A), (B), (C), 0, 0, 0)

// 0.125 (1/sqrt(64)) * log2(e), folded into Q at projection time so the
// attention kernel can use exp2 directly. Power-of-2 part is exact; the
// log2e factor replaces one bf16 rounding with another (no extra error).
#define QSCALE 0.18033688011112042f

// ---------------------------------------------------------------------------
// Kernel 1: fused QKV projection.
//   x [32768][768] fp32  x  W[768][64] (q,k,v) -> Q (pre-scaled), K bf16
//   [32768][64], V transposed per batch: Vt [8][64][4096] bf16.
// ---------------------------------------------------------------------------
__global__ __launch_bounds__(256) void qkv_proj_kernel(
    const float* __restrict__ x,
    const float* __restrict__ Wq, const float* __restrict__ bq,
    const float* __restrict__ Wk, const float* __restrict__ bk,
    const float* __restrict__ Wv, const float* __restrict__ bv,
    __bf16* __restrict__ Qg, __bf16* __restrict__ Kg, __bf16* __restrict__ Vtg)
{
    __shared__ __bf16 xs[64][40];    // [row][k]  pad 32->40
    __shared__ __bf16 wt[192][40];   // [col][k]  transposed W tile

    const int tid  = threadIdx.x;
    const int wid  = tid >> 6;
    const int lane = tid & 63;
    const int l15  = lane & 15;
    const int l4   = lane >> 4;
    const int m0   = blockIdx.x * 64;

    f32x4 acc[4][3];
    #pragma unroll
    for (int i = 0; i < 4; ++i)
        #pragma unroll
        for (int j = 0; j < 3; ++j)
            acc[i][j] = (f32x4){0.f, 0.f, 0.f, 0.f};

    for (int k0 = 0; k0 < 768; k0 += 32) {
        #pragma unroll
        for (int i = 0; i < 2; ++i) {
            int idx = tid + 256 * i;       // 0..511
            int row = idx >> 3;            // 64 rows
            int c4  = idx & 7;             // 8 float4 per row
            const float4 v = *reinterpret_cast<const float4*>(
                x + (size_t)(m0 + row) * 768 + k0 + c4 * 4);
            bf16x4 t;
            t[0] = (__bf16)v.x; t[1] = (__bf16)v.y;
            t[2] = (__bf16)v.z; t[3] = (__bf16)v.w;
            *reinterpret_cast<bf16x4*>(&xs[row][c4 * 4]) = t;
        }
        #pragma unroll
        for (int i = 0; i < 6; ++i) {
            int idx = tid + 256 * i;       // 0..1535
            int kg  = idx / 192;           // 0..7
            int c   = idx - kg * 192;      // 0..191
            const float* Wm = (c < 64) ? Wq : ((c < 128) ? Wk : Wv);
            int cc = c & 63;
            bf16x4 t;
            #pragma unroll
            for (int j = 0; j < 4; ++j)
                t[j] = (__bf16)Wm[(size_t)(k0 + kg * 4 + j) * 64 + cc];
            *reinterpret_cast<bf16x4*>(&wt[c][kg * 4]) = t;
        }
        __syncthreads();

        bf16x8 afrag[4];
        #pragma unroll
        for (int rf = 0; rf < 4; ++rf)
            afrag[rf] = *reinterpret_cast<const bf16x8*>(&xs[rf * 16 + l15][l4 * 8]);
        #pragma unroll
        for (int cf = 0; cf < 3; ++cf) {
            bf16x8 bfrag = *reinterpret_cast<const bf16x8*>(
                &wt[wid * 48 + cf * 16 + l15][l4 * 8]);
            #pragma unroll
            for (int rf = 0; rf < 4; ++rf)
                acc[rf][cf] = MFMA16(afrag[rf], bfrag, acc[rf][cf]);
        }
        __syncthreads();
    }

    #pragma unroll
    for (int cf = 0; cf < 3; ++cf) {
        int col = wid * 48 + cf * 16 + l15;   // 0..191
        int mi  = col >> 6;                   // 0=Q 1=K 2=V
        int h   = col & 63;
        float bias = (mi == 0) ? bq[h] : ((mi == 1) ? bk[h] : bv[h]);
        float scl  = (mi == 0) ? QSCALE : 1.0f;
        #pragma unroll
        for (int rf = 0; rf < 4; ++rf) {
            int r0 = rf * 16 + l4 * 4;
            if (mi == 2) {
                int m  = m0 + r0;
                int bb = m >> 12;
                int n0 = m & 4095;
                bf16x4 t;
                #pragma unroll
                for (int r = 0; r < 4; ++r)
                    t[r] = (__bf16)(acc[rf][cf][r] + bias);
                *reinterpret_cast<bf16x4*>(
                    Vtg + ((size_t)bb * 64 + h) * 4096 + n0) = t;
            } else {
                __bf16* G = (mi == 0) ? Qg : Kg;
                #pragma unroll
                for (int r = 0; r < 4; ++r)
                    G[(size_t)(m0 + r0 + r) * 64 + h] =
                        (__bf16)((acc[rf][cf][r] + bias) * scl);
            }
        }
    }
}

// ---------------------------------------------------------------------------
// Kernel 2: flash attention, swapped-QK^T, P fully in registers.
// Block = 1 batch x 64 q rows, 4 waves (16 q each). KBLK=64.
// LDS: double-buffered K,Vt tiles [64][64] bf16 with granule-XOR swizzle.
//   Swizzle: 8-elem granule index g stored at g ^ (row & 7).
// QK^T swapped: S^T = mfma(A=K, B=Q) -> lane holds P[q=l15][16cf+4*l4+r].
// PV uses a permuted k-order so A-frag is a pure in-lane repack of s regs:
//   slot s=8*l4+j  <->  key kc*32 + 16*(j>>2) + 4*l4 + (j&3)
//   B-frag (V) read as 2x ds_read_b64 at matching permuted columns.
// ---------------------------------------------------------------------------
__global__ __launch_bounds__(256) void attn_kernel(
    const __bf16* __restrict__ Qg, const __bf16* __restrict__ Kg,
    const __bf16* __restrict__ Vtg, float* __restrict__ out)
{
    __shared__ __bf16 ks[2][64][64];
    __shared__ __bf16 vs[2][64][64];

    const int tid  = threadIdx.x;
    const int wid  = tid >> 6;
    const int lane = tid & 63;
    const int l15  = lane & 15;
    const int l4   = lane >> 4;
    const int b    = blockIdx.x >> 6;          // batch
    const int q0   = (blockIdx.x & 63) * 64;   // q-tile base
    const int qw   = q0 + wid * 16;            // this wave's q rows

    // Q fragment (used as B operand of swapped QK^T): lane holds
    // Q[qw+l15][dc*32 + l4*8 + j]  (Q pre-scaled by QSCALE)
    bf16x8 aq[2];
    #pragma unroll
    for (int dc = 0; dc < 2; ++dc)
        aq[dc] = *reinterpret_cast<const bf16x8*>(
            Qg + (size_t)(b * 4096 + qw + l15) * 64 + dc * 32 + l4 * 8);

    const __bf16* Kbase = Kg  + (size_t)b * 4096 * 64;
    const __bf16* Vbase = Vtg + (size_t)b * 64 * 4096;

    float m_r = -1e30f, l_r = 0.f;
    f32x4 o[4];
    #pragma unroll
    for (int cf = 0; cf < 4; ++cf) o[cf] = (f32x4){0.f, 0.f, 0.f, 0.f};

    // staging registers (this wave stages local rows [wid*16, wid*16+16))
    bf16x8 kreg[2], vreg[2];
    const int srow_base = wid * 16 + (lane >> 3);  // + c*8
    const int c8 = lane & 7;

    auto stage_load = [&](int kt) {
        #pragma unroll
        for (int c = 0; c < 2; ++c) {
            int r = srow_base + c * 8;
            kreg[c] = *reinterpret_cast<const bf16x8*>(
                Kbase + (size_t)(kt * 64 + r) * 64 + c8 * 8);
            vreg[c] = *reinterpret_cast<const bf16x8*>(
                Vbase + (size_t)r * 4096 + kt * 64 + c8 * 8);
        }
    };
    auto stage_write = [&](int buf) {
        #pragma unroll
        for (int c = 0; c < 2; ++c) {
            int r = srow_base + c * 8;
            int g = c8 ^ (r & 7);
            *reinterpret_cast<bf16x8*>(&ks[buf][r][g * 8]) = kreg[c];
            *reinterpret_cast<bf16x8*>(&vs[buf][r][g * 8]) = vreg[c];
        }
    };

    stage_load(0);
    stage_write(0);

    for (int kt = 0; kt < 64; ++kt) {
        __syncthreads();
        const int buf = kt & 1;
        const bool pre = (kt + 1) < 64;
        if (pre) stage_load(kt + 1);

        // ---- S^T = K * Q^T (swapped): s[cf][r] = S2[q=l15][key cf*16+4*l4+r]
        f32x4 s[4];
        #pragma unroll
        for (int cf = 0; cf < 4; ++cf) s[cf] = (f32x4){0.f, 0.f, 0.f, 0.f};
        #pragma unroll
        for (int dc = 0; dc < 2; ++dc) {
            #pragma unroll
            for (int cf = 0; cf < 4; ++cf) {
                int row = cf * 16 + l15;
                int g   = (dc * 4 + l4) ^ (row & 7);
                bf16x8 kf = *reinterpret_cast<const bf16x8*>(&ks[buf][row][g * 8]);
                s[cf] = MFMA16(kf, aq[dc], s[cf]);
            }
        }

        // ---- online softmax (base-2), per-lane row q = l15
        float pm = s[0][0];
        #pragma unroll
        for (int cf = 0; cf < 4; ++cf)
            #pragma unroll
            for (int r = 0; r < 4; ++r)
                pm = fmaxf(pm, s[cf][r]);
        pm = fmaxf(pm, __shfl_xor(pm, 16));
        pm = fmaxf(pm, __shfl_xor(pm, 32));

        float mnew = fmaxf(m_r, pm);
        float fr   = exp2f(m_r - mnew);
        m_r = mnew;

        float psum = 0.f;
        #pragma unroll
        for (int cf = 0; cf < 4; ++cf)
            #pragma unroll
            for (int r = 0; r < 4; ++r) {
                float p = exp2f(s[cf][r] - m_r);
                s[cf][r] = p;
                psum += p;
            }
        psum += __shfl_xor(psum, 16);
        psum += __shfl_xor(psum, 32);
        l_r = l_r * fr + psum;

        // O-rows live at q = 4*l4+r; fetch their rescale factors
        float frq[4];
        #pragma unroll
        for (int r = 0; r < 4; ++r)
            frq[r] = __shfl(fr, l4 * 4 + r);
        #pragma unroll
        for (int cf = 0; cf < 4; ++cf)
            #pragma unroll
            for (int r = 0; r < 4; ++r)
                o[cf][r] *= frq[r];

        // ---- P -> bf16 A-fragments, pure in-lane repack
        bf16x8 pa[2];
        #pragma unroll
        for (int kc = 0; kc < 2; ++kc)
            #pragma unroll
            for (int j = 0; j < 4; ++j) {
                pa[kc][j]     = (__bf16)s[2 * kc][j];
                pa[kc][j + 4] = (__bf16)s[2 * kc + 1][j];
            }

        // ---- O += P * V with permuted k-order
        #pragma unroll
        for (int kc = 0; kc < 2; ++kc)
            #pragma unroll
            for (int cf = 0; cf < 4; ++cf) {
                int row = cf * 16 + l15;
                int rs  = row & 7;
                int off = (l4 & 1) * 4;
                int g0  = ((kc * 4 + (l4 >> 1)) ^ rs) * 8 + off;
                int g1  = ((kc * 4 + 2 + (l4 >> 1)) ^ rs) * 8 + off;
                bf16x4 b0 = *reinterpret_cast<const bf16x4*>(&vs[buf][row][g0]);
                bf16x4 b1 = *reinterpret_cast<const bf16x4*>(&vs[buf][row][g1]);
                bf16x8 bv;
                #pragma unroll
                for (int j = 0; j < 4; ++j) { bv[j] = b0[j]; bv[j + 4] = b1[j]; }
                o[cf] = MFMA16(pa[kc], bv, o[cf]);
            }

        if (pre) stage_write(buf ^ 1);
    }

    // epilogue: normalize rows (q = 4*l4+r) and store fp32
    float lq[4];
    #pragma unroll
    for (int r = 0; r < 4; ++r)
        lq[r] = 1.0f / __shfl(l_r, l4 * 4 + r);
    #pragma unroll
    for (int cf = 0; cf < 4; ++cf)
        #pragma unroll
        for (int r = 0; r < 4; ++r)
            out[(size_t)(b * 4096 + qw + l4 * 4 + r) * 64 + cf * 16 + l15] =
                o[cf][r] * lq[r];
}

extern "C" void kernel_launch(void* const* d_in, const int* in_sizes, int n_in,
                              void* d_out, int out_size, void* d_ws, size_t ws_size,
                              hipStream_t stream)
{
    (void)in_sizes; (void)n_in; (void)out_size; (void)ws_size;
    const float* x  = (const float*)d_in[0];
    const float* Wq = (const float*)d_in[1];
    const float* bq = (const float*)d_in[2];
    const float* Wk = (const float*)d_in[3];
    const float* bk = (const float*)d_in[4];
    const float* Wv = (const float*)d_in[5];
    const float* bv = (const float*)d_in[6];
    float* out = (float*)d_out;

    __bf16* Qg  = (__bf16*)d_ws;                    // [32768][64] bf16 (scaled)
    __bf16* Kg  = Qg + (size_t)32768 * 64;          // [32768][64] bf16
    __bf16* Vtg = Kg + (size_t)32768 * 64;          // [8][64][4096] bf16

    qkv_proj_kernel<<<512, 256, 0, stream>>>(x, Wq, bq, Wk, bk, Wv, bv, Qg, Kg, Vtg);
    attn_kernel<<<512, 256, 0, stream>>>(Qg, Kg, Vtg, out);
}